// Round 1
// baseline (414.752 us; speedup 1.0000x reference)
//
#include <hip/hip_runtime.h>

typedef unsigned short u16;
typedef unsigned int u32;
typedef __bf16 bf16x8 __attribute__((ext_vector_type(8)));
typedef float f32x4 __attribute__((ext_vector_type(4)));
typedef unsigned short u16x4 __attribute__((ext_vector_type(4)));

#define AS1(p) ((const __attribute__((address_space(1))) void*)(p))
#define AS3(p) ((__attribute__((address_space(3))) void*)(p))

__device__ __forceinline__ u16 f2bf(float x) {
  u32 u = __float_as_uint(x);
  u32 r = u + 0x7fffu + ((u >> 16) & 1u);
  return (u16)(r >> 16);
}
__device__ __forceinline__ float bf2f(u16 h) {
  return __uint_as_float(((u32)h) << 16);
}

// ---------------------------------------------------------------------------
// Elementwise: split fp32 -> (bf16 hi, bf16 lo) for q,k; bf16 for v.
// ---------------------------------------------------------------------------
__device__ __forceinline__ void split4(float4 x, u16x4& h, u16x4& l) {
  float xs[4] = {x.x, x.y, x.z, x.w};
#pragma unroll
  for (int e = 0; e < 4; ++e) {
    u16 hh = f2bf(xs[e]);
    h[e] = hh;
    l[e] = f2bf(xs[e] - bf2f(hh));
  }
}

__global__ __launch_bounds__(256) void split_qkv(
    const float* __restrict__ q, const float* __restrict__ k,
    const float* __restrict__ v, u16* __restrict__ qh, u16* __restrict__ ql,
    u16* __restrict__ kh, u16* __restrict__ kl, u16* __restrict__ vb, int n4) {
  int stride = gridDim.x * blockDim.x;
  for (int i = blockIdx.x * blockDim.x + threadIdx.x; i < n4; i += stride) {
    u16x4 h, l;
    float4 x = ((const float4*)q)[i];
    split4(x, h, l);
    ((u16x4*)qh)[i] = h;
    ((u16x4*)ql)[i] = l;
    x = ((const float4*)k)[i];
    split4(x, h, l);
    ((u16x4*)kh)[i] = h;
    ((u16x4*)kl)[i] = l;
    x = ((const float4*)v)[i];
    u16x4 hb;
    hb[0] = f2bf(x.x); hb[1] = f2bf(x.y); hb[2] = f2bf(x.z); hb[3] = f2bf(x.w);
    ((u16x4*)vb)[i] = hb;
  }
}

// Transpose + split weights: wqt[e][d] = split(Wq[d][e]); wot[e][d] = bf16(Wo[d][e])
__global__ __launch_bounds__(256) void prep_w(
    const float* __restrict__ Wq, const float* __restrict__ Wo,
    u16* __restrict__ wqt_h, u16* __restrict__ wqt_l, u16* __restrict__ wot,
    int D) {
  int idx = blockIdx.x * 256 + threadIdx.x;  // idx = e*D + d
  if (idx >= D * D) return;
  int e = idx / D, d = idx % D;
  float x = Wq[(size_t)d * D + e];
  u16 h = f2bf(x);
  wqt_h[idx] = h;
  wqt_l[idx] = f2bf(x - bf2f(h));
  wot[idx] = f2bf(Wo[(size_t)d * D + e]);
}

// Batched bf16 transpose: out[z][c][r] = in[z][r][c]
__global__ void transpose_bf16(const u16* __restrict__ in, u16* __restrict__ out,
                               int R, int C) {
  __shared__ u16 tile[32][33];
  size_t zoff = (size_t)blockIdx.z * R * C;
  int c0 = blockIdx.x * 32, r0 = blockIdx.y * 32;
  int tx = threadIdx.x, ty = threadIdx.y;
#pragma unroll
  for (int i = ty; i < 32; i += 8)
    tile[i][tx] = in[zoff + (size_t)(r0 + i) * C + (c0 + tx)];
  __syncthreads();
#pragma unroll
  for (int i = ty; i < 32; i += 8)
    out[zoff + (size_t)(c0 + i) * R + (r0 + tx)] = tile[tx][i];
}

// ---------------------------------------------------------------------------
// GEMM: C[m][n] = sum_k A[m][k] * Bt[n][k]  (+bias[n]); both operands K-major.
// SPLIT: A,Bt given as hi/lo bf16 pairs -> 3-term Markidis accumulation.
// EPI: 0 = fp32, 1 = bf16, 2 = bf16 hi/lo split.
// BM=BN=128, BK=32, 256 threads (4 waves, 2x2), mfma_f32_16x16x32_bf16.
// ---------------------------------------------------------------------------
template <bool SPLIT, int EPI>
__global__ __launch_bounds__(256, 2) void gemm_bt(
    const u16* __restrict__ Ah, const u16* __restrict__ Al,
    const u16* __restrict__ Bh, const u16* __restrict__ Bl,
    const float* __restrict__ bias, float* __restrict__ Cf,
    u16* __restrict__ Ch, u16* __restrict__ Cl, int M, int N, int K,
    long long sA, long long sB, long long sC) {
  constexpr int NT = SPLIT ? 2 : 1;
  __shared__ alignas(16) u16 As[NT][128 * 32];
  __shared__ alignas(16) u16 Bs[NT][128 * 32];

  const int t = threadIdx.x;
  const int lane = t & 63;
  const int w = t >> 6;
  const int wr = w >> 1, wc = w & 1;

  const long long zb = blockIdx.z;
  const u16* pA[2];
  const u16* pB[2];
  pA[0] = Ah + zb * sA;
  pB[0] = Bh + zb * sB;
  pA[1] = SPLIT ? (Al + zb * sA) : nullptr;
  pB[1] = SPLIT ? (Bl + zb * sB) : nullptr;

  const int m0 = blockIdx.x * 128;
  const int n0 = blockIdx.y * 128;

  f32x4 acc[4][4] = {};

  // staging: 2 rounds of 256 lanes x 16B cover 128x32 bf16 (8KB)
  const int row0 = t >> 2;
  const int colS = (t & 3) * 8;
  const int lds0 = (t & ~63) * 8;          // elements; wave-uniform base
  const int lds1 = (256 + (t & ~63)) * 8;

  const size_t aoff0 = (size_t)(m0 + row0) * K + colS;
  const size_t aoff1 = (size_t)(m0 + row0 + 64) * K + colS;
  const size_t boff0 = (size_t)(n0 + row0) * K + colS;
  const size_t boff1 = (size_t)(n0 + row0 + 64) * K + colS;

  for (int k0 = 0; k0 < K; k0 += 32) {
    __syncthreads();
#pragma unroll
    for (int p = 0; p < NT; ++p) {
      __builtin_amdgcn_global_load_lds(AS1(pA[p] + aoff0 + k0), AS3(&As[p][lds0]), 16, 0, 0);
      __builtin_amdgcn_global_load_lds(AS1(pA[p] + aoff1 + k0), AS3(&As[p][lds1]), 16, 0, 0);
      __builtin_amdgcn_global_load_lds(AS1(pB[p] + boff0 + k0), AS3(&Bs[p][lds0]), 16, 0, 0);
      __builtin_amdgcn_global_load_lds(AS1(pB[p] + boff1 + k0), AS3(&Bs[p][lds1]), 16, 0, 0);
    }
    __syncthreads();

    const int fr = lane & 15;
    const int kc = (lane >> 4) * 8;
    bf16x8 a[4], b[4];
#pragma unroll
    for (int i = 0; i < 4; ++i)
      a[i] = *(const bf16x8*)&As[0][(wr * 64 + i * 16 + fr) * 32 + kc];
#pragma unroll
    for (int j = 0; j < 4; ++j)
      b[j] = *(const bf16x8*)&Bs[0][(wc * 64 + j * 16 + fr) * 32 + kc];

    if constexpr (SPLIT) {
      bf16x8 al[4], bl[4];
#pragma unroll
      for (int i = 0; i < 4; ++i)
        al[i] = *(const bf16x8*)&As[1][(wr * 64 + i * 16 + fr) * 32 + kc];
#pragma unroll
      for (int j = 0; j < 4; ++j)
        bl[j] = *(const bf16x8*)&Bs[1][(wc * 64 + j * 16 + fr) * 32 + kc];
#pragma unroll
      for (int i = 0; i < 4; ++i)
#pragma unroll
        for (int j = 0; j < 4; ++j) {
          acc[i][j] = __builtin_amdgcn_mfma_f32_16x16x32_bf16(a[i], b[j], acc[i][j], 0, 0, 0);
          acc[i][j] = __builtin_amdgcn_mfma_f32_16x16x32_bf16(a[i], bl[j], acc[i][j], 0, 0, 0);
          acc[i][j] = __builtin_amdgcn_mfma_f32_16x16x32_bf16(al[i], b[j], acc[i][j], 0, 0, 0);
        }
    } else {
#pragma unroll
      for (int i = 0; i < 4; ++i)
#pragma unroll
        for (int j = 0; j < 4; ++j)
          acc[i][j] = __builtin_amdgcn_mfma_f32_16x16x32_bf16(a[i], b[j], acc[i][j], 0, 0, 0);
    }
  }

  // epilogue: C/D map col=lane&15, row=(lane>>4)*4+reg
  const int er = (lane >> 4) * 4;
  const int ec = lane & 15;
#pragma unroll
  for (int j = 0; j < 4; ++j) {
    const int gcol = n0 + wc * 64 + j * 16 + ec;
    const float bv = bias ? bias[gcol] : 0.0f;
#pragma unroll
    for (int i = 0; i < 4; ++i) {
      const int grow0 = m0 + wr * 64 + i * 16 + er;
#pragma unroll
      for (int r = 0; r < 4; ++r) {
        const float x = acc[i][j][r] + bv;
        const size_t off = (size_t)zb * sC + (size_t)(grow0 + r) * N + gcol;
        if constexpr (EPI == 0) {
          Cf[off] = x;
        } else if constexpr (EPI == 1) {
          Ch[off] = f2bf(x);
        } else {
          const u16 h = f2bf(x);
          Ch[off] = h;
          Cl[off] = f2bf(x - bf2f(h));
        }
      }
    }
  }
}

// ---------------------------------------------------------------------------
// Row softmax: in-place fp32 (weights output) + bf16 copy (P for PV GEMM).
// One 256-thread block per row of T=2048.
// ---------------------------------------------------------------------------
__global__ __launch_bounds__(256) void softmax_rows(float* __restrict__ S,
                                                    u16* __restrict__ P) {
  const int T = 2048;
  const size_t row = blockIdx.x;
  float* sr = S + row * T;
  u16* pr = P + row * T;
  const int t = threadIdx.x;
  const int w = t >> 6, lane = t & 63;
  __shared__ float red[8];

  float v[8];
  float mx = -1e30f;
#pragma unroll
  for (int i = 0; i < 8; ++i) {
    v[i] = sr[t + 256 * i];
    mx = fmaxf(mx, v[i]);
  }
#pragma unroll
  for (int off = 32; off; off >>= 1) mx = fmaxf(mx, __shfl_xor(mx, off));
  if (lane == 0) red[w] = mx;
  __syncthreads();
  mx = fmaxf(fmaxf(red[0], red[1]), fmaxf(red[2], red[3]));

  float s = 0.f;
#pragma unroll
  for (int i = 0; i < 8; ++i) {
    v[i] = __expf(v[i] - mx);
    s += v[i];
  }
#pragma unroll
  for (int off = 32; off; off >>= 1) s += __shfl_xor(s, off);
  if (lane == 0) red[4 + w] = s;
  __syncthreads();
  s = (red[4] + red[5]) + (red[6] + red[7]);
  const float inv = 1.0f / s;
#pragma unroll
  for (int i = 0; i < 8; ++i) {
    const float wv = v[i] * inv;
    sr[t + 256 * i] = wv;
    pr[t + 256 * i] = f2bf(wv);
  }
}

// ---------------------------------------------------------------------------
extern "C" void kernel_launch(void* const* d_in, const int* in_sizes, int n_in,
                              void* d_out, int out_size, void* d_ws,
                              size_t ws_size, hipStream_t stream) {
  (void)in_sizes; (void)n_in; (void)out_size; (void)ws_size;
  const float* query = (const float*)d_in[0];
  const float* key   = (const float*)d_in[1];
  const float* value = (const float*)d_in[2];
  const float* Wq    = (const float*)d_in[3];
  const float* bq    = (const float*)d_in[4];
  const float* Wo    = (const float*)d_in[5];
  const float* bo    = (const float*)d_in[6];

  const int S = 2048, D = 1024;
  const size_t n = (size_t)4 * S * D;  // 8,388,608

  float* out = (float*)d_out;
  float* wts = out + n;  // 16,777,216 floats (B,S,T)

  char* ws = (char*)d_ws;
  u16* wqt_h = (u16*)(ws);
  u16* wqt_l = (u16*)(ws + (2ull << 20));
  u16* wot   = (u16*)(ws + (4ull << 20));
  u16* vin   = (u16*)(ws + (6ull << 20));   // later reused as ctx
  u16* Qh = (u16*)(ws + (22ull << 20));
  u16* Ql = (u16*)(ws + (38ull << 20));
  u16* Kh = (u16*)(ws + (54ull << 20));
  u16* Kl = (u16*)(ws + (70ull << 20));     // total ws use: 86 MB
  u16* P = Qh;      // 32MB over Qh+Ql (dead after score GEMM)
  u16* ctxb = vin;  // 16MB (vin dead after V projection)

  // scratch in d_out: weights region holds input splits until score GEMM;
  // out region holds V / V^T until final GEMM.
  u16* qin_h = (u16*)wts;
  u16* qin_l = qin_h + n;
  u16* kin_h = qin_l + n;
  u16* kin_l = kin_h + n;
  u16* Vp = (u16*)out;
  u16* Vt = Vp + n;

  // 1. split q,k inputs; bf16 v
  split_qkv<<<2048, 256, 0, stream>>>(query, key, value, qin_h, qin_l, kin_h,
                                      kin_l, vin, (int)(n / 4));
  // 2. weight transpose+split
  prep_w<<<(D * D) / 256, 256, 0, stream>>>(Wq, Wo, wqt_h, wqt_l, wot, D);
  // 3. Q = query @ Wq + bq  (split in, split out)
  gemm_bt<true, 2><<<dim3(64, 8, 1), 256, 0, stream>>>(
      qin_h, qin_l, wqt_h, wqt_l, bq, nullptr, Qh, Ql, 8192, 1024, 1024, 0, 0, 0);
  // 4. K = key @ Wq + bq
  gemm_bt<true, 2><<<dim3(64, 8, 1), 256, 0, stream>>>(
      kin_h, kin_l, wqt_h, wqt_l, bq, nullptr, Kh, Kl, 8192, 1024, 1024, 0, 0, 0);
  // 5. V = value @ Wq + bq  (plain bf16)
  gemm_bt<false, 1><<<dim3(64, 8, 1), 256, 0, stream>>>(
      vin, nullptr, wqt_h, nullptr, bq, nullptr, Vp, nullptr, 8192, 1024, 1024, 0, 0, 0);
  // 6. V^T per batch (2048x1024 -> 1024x2048)
  transpose_bf16<<<dim3(1024 / 32, 2048 / 32, 4), dim3(32, 8), 0, stream>>>(
      Vp, Vt, 2048, 1024);
  // 7. score = Q @ K^T (split, fp32 out into weights region)
  gemm_bt<true, 0><<<dim3(16, 16, 4), 256, 0, stream>>>(
      Qh, Ql, Kh, Kl, nullptr, wts, nullptr, nullptr, 2048, 2048, 1024,
      (long long)S * D, (long long)S * D, (long long)S * S);
  // 8. softmax rows (in-place) + bf16 P
  softmax_rows<<<8192, 256, 0, stream>>>(wts, P);
  // 9. ctx = P @ V  (Bt = V^T)
  gemm_bt<false, 1><<<dim3(16, 8, 4), 256, 0, stream>>>(
      P, nullptr, Vt, nullptr, nullptr, nullptr, ctxb, nullptr, 2048, 1024, 2048,
      (long long)S * S, (long long)D * S, (long long)S * D);
  // 10. out = ctx @ Wo + bo (fp32 out)
  gemm_bt<false, 0><<<dim3(64, 8, 1), 256, 0, stream>>>(
      ctxb, nullptr, wot, nullptr, bo, out, nullptr, nullptr, 8192, 1024, 1024,
      0, 0, 0);
}

// Round 2
// 353.736 us; speedup vs baseline: 1.1725x; 1.1725x over previous
//
#include <hip/hip_runtime.h>

typedef unsigned short u16;
typedef unsigned int u32;
typedef __bf16 bf16x8 __attribute__((ext_vector_type(8)));
typedef float f32x4 __attribute__((ext_vector_type(4)));
typedef unsigned short u16x4 __attribute__((ext_vector_type(4)));

#define AS1(p) ((const __attribute__((address_space(1))) void*)(p))
#define AS3(p) ((__attribute__((address_space(3))) void*)(p))

__device__ __forceinline__ u16 f2bf(float x) {
  u32 u = __float_as_uint(x);
  u32 r = u + 0x7fffu + ((u >> 16) & 1u);
  return (u16)(r >> 16);
}
__device__ __forceinline__ float bf2f(u16 h) {
  return __uint_as_float(((u32)h) << 16);
}

// ---------------------------------------------------------------------------
// Elementwise: split fp32 -> (bf16 hi, bf16 lo) for q,k; bf16 for v.
// ---------------------------------------------------------------------------
__device__ __forceinline__ void split4(float4 x, u16x4& h, u16x4& l) {
  float xs[4] = {x.x, x.y, x.z, x.w};
#pragma unroll
  for (int e = 0; e < 4; ++e) {
    u16 hh = f2bf(xs[e]);
    h[e] = hh;
    l[e] = f2bf(xs[e] - bf2f(hh));
  }
}

__global__ __launch_bounds__(256) void split_qkv(
    const float* __restrict__ q, const float* __restrict__ k,
    const float* __restrict__ v, u16* __restrict__ qh, u16* __restrict__ ql,
    u16* __restrict__ kh, u16* __restrict__ kl, u16* __restrict__ vb, int n4) {
  int stride = gridDim.x * blockDim.x;
  for (int i = blockIdx.x * blockDim.x + threadIdx.x; i < n4; i += stride) {
    u16x4 h, l;
    float4 x = ((const float4*)q)[i];
    split4(x, h, l);
    ((u16x4*)qh)[i] = h;
    ((u16x4*)ql)[i] = l;
    x = ((const float4*)k)[i];
    split4(x, h, l);
    ((u16x4*)kh)[i] = h;
    ((u16x4*)kl)[i] = l;
    x = ((const float4*)v)[i];
    u16x4 hb;
    hb[0] = f2bf(x.x); hb[1] = f2bf(x.y); hb[2] = f2bf(x.z); hb[3] = f2bf(x.w);
    ((u16x4*)vb)[i] = hb;
  }
}

// Tiled transpose+split of weights: wqt[e][d] = split(Wq[d][e]); wot = bf16(Wo^T)
__global__ void prep_w_t(const float* __restrict__ Wq,
                         const float* __restrict__ Wo, u16* __restrict__ wqt_h,
                         u16* __restrict__ wqt_l, u16* __restrict__ wot,
                         int D) {
  __shared__ float tq[32][33];
  __shared__ float to[32][33];
  int c0 = blockIdx.x * 32, r0 = blockIdx.y * 32;
  int tx = threadIdx.x, ty = threadIdx.y;
#pragma unroll
  for (int i = ty; i < 32; i += 8) {
    tq[i][tx] = Wq[(size_t)(r0 + i) * D + c0 + tx];
    to[i][tx] = Wo[(size_t)(r0 + i) * D + c0 + tx];
  }
  __syncthreads();
#pragma unroll
  for (int i = ty; i < 32; i += 8) {
    float x = tq[tx][i];  // = Wq[(r0+tx)][c0+i]
    u16 h = f2bf(x);
    size_t o = (size_t)(c0 + i) * D + r0 + tx;
    wqt_h[o] = h;
    wqt_l[o] = f2bf(x - bf2f(h));
    wot[o] = f2bf(to[tx][i]);
  }
}

// Batched bf16 transpose: out[z][c][r] = in[z][r][c]
__global__ void transpose_bf16(const u16* __restrict__ in, u16* __restrict__ out,
                               int R, int C) {
  __shared__ u16 tile[32][33];
  size_t zoff = (size_t)blockIdx.z * R * C;
  int c0 = blockIdx.x * 32, r0 = blockIdx.y * 32;
  int tx = threadIdx.x, ty = threadIdx.y;
#pragma unroll
  for (int i = ty; i < 32; i += 8)
    tile[i][tx] = in[zoff + (size_t)(r0 + i) * C + (c0 + tx)];
  __syncthreads();
#pragma unroll
  for (int i = ty; i < 32; i += 8)
    out[zoff + (size_t)(c0 + i) * R + (r0 + tx)] = tile[tx][i];
}

// ---------------------------------------------------------------------------
// Round-1 128x128 GEMM (kept for the small plain GEMMs: Vproj / ctx / outproj)
// C[m][n] = sum_k A[m][k]*Bt[n][k] (+bias); EPI: 0=f32, 1=bf16.
// ---------------------------------------------------------------------------
template <int EPI>
__global__ __launch_bounds__(256, 2) void gemm_bt(
    const u16* __restrict__ Ah, const u16* __restrict__ Bh,
    const float* __restrict__ bias, float* __restrict__ Cf,
    u16* __restrict__ Ch, int M, int N, int K,
    long long sA, long long sB, long long sC) {
  __shared__ alignas(16) u16 As[128 * 32];
  __shared__ alignas(16) u16 Bs[128 * 32];

  const int t = threadIdx.x;
  const int lane = t & 63;
  const int w = t >> 6;
  const int wr = w >> 1, wc = w & 1;

  const long long zb = blockIdx.z;
  const u16* pA = Ah + zb * sA;
  const u16* pB = Bh + zb * sB;

  const int m0 = blockIdx.x * 128;
  const int n0 = blockIdx.y * 128;

  f32x4 acc[4][4] = {};

  const int row0 = t >> 2;
  const int colS = (t & 3) * 8;
  const int lds0 = (t & ~63) * 8;
  const int lds1 = (256 + (t & ~63)) * 8;

  const size_t aoff0 = (size_t)(m0 + row0) * K + colS;
  const size_t aoff1 = (size_t)(m0 + row0 + 64) * K + colS;
  const size_t boff0 = (size_t)(n0 + row0) * K + colS;
  const size_t boff1 = (size_t)(n0 + row0 + 64) * K + colS;

  for (int k0 = 0; k0 < K; k0 += 32) {
    __syncthreads();
    __builtin_amdgcn_global_load_lds(AS1(pA + aoff0 + k0), AS3(&As[lds0]), 16, 0, 0);
    __builtin_amdgcn_global_load_lds(AS1(pA + aoff1 + k0), AS3(&As[lds1]), 16, 0, 0);
    __builtin_amdgcn_global_load_lds(AS1(pB + boff0 + k0), AS3(&Bs[lds0]), 16, 0, 0);
    __builtin_amdgcn_global_load_lds(AS1(pB + boff1 + k0), AS3(&Bs[lds1]), 16, 0, 0);
    __syncthreads();

    const int fr = lane & 15;
    const int kc = (lane >> 4) * 8;
    bf16x8 a[4], b[4];
#pragma unroll
    for (int i = 0; i < 4; ++i)
      a[i] = *(const bf16x8*)&As[(wr * 64 + i * 16 + fr) * 32 + kc];
#pragma unroll
    for (int j = 0; j < 4; ++j)
      b[j] = *(const bf16x8*)&Bs[(wc * 64 + j * 16 + fr) * 32 + kc];
#pragma unroll
    for (int i = 0; i < 4; ++i)
#pragma unroll
      for (int j = 0; j < 4; ++j)
        acc[i][j] = __builtin_amdgcn_mfma_f32_16x16x32_bf16(a[i], b[j], acc[i][j], 0, 0, 0);
  }

  const int er = (lane >> 4) * 4;
  const int ec = lane & 15;
#pragma unroll
  for (int j = 0; j < 4; ++j) {
    const int gcol = n0 + wc * 64 + j * 16 + ec;
    const float bv = bias ? bias[gcol] : 0.0f;
#pragma unroll
    for (int i = 0; i < 4; ++i) {
      const int grow0 = m0 + wr * 64 + i * 16 + er;
#pragma unroll
      for (int r = 0; r < 4; ++r) {
        const float x = acc[i][j][r] + bv;
        const size_t off = (size_t)zb * sC + (size_t)(grow0 + r) * N + gcol;
        if constexpr (EPI == 0) Cf[off] = x;
        else Ch[off] = f2bf(x);
      }
    }
  }
}

// ---------------------------------------------------------------------------
// 256x256 8-phase split GEMM (Markidis 3-term), BK=32 real K per tile packed
// as 64 virtual-K (hi chunks 0-3, lo chunks 4-7). 512 threads (8 waves, 2x4),
// 128 KiB dynamic LDS (double-buffered), XOR-swizzled LDS, counted vmcnt(4),
// setprio around MFMA clusters. EPI: 0 = f32 out, 2 = bf16 hi/lo split out.
// ---------------------------------------------------------------------------
#define A_LDS(BUF, H) ((BUF) * 32768 + (H) * 8192)
#define B_LDS(BUF, H) ((BUF) * 32768 + 16384 + (H) * 8192)

#define STAGE(DSTBASE, SH, SL, ROWBASE, KREAL)                                 \
  do {                                                                         \
    const u16* s0_ = (sc < 4 ? (SH) : (SL)) +                                  \
                     (size_t)((ROWBASE) + sr) * K + (KREAL) + ((sc & 3) << 3); \
    const u16* s1_ = s0_ + (size_t)64 * K;                                     \
    __builtin_amdgcn_global_load_lds(AS1(s0_), AS3(&lds[(DSTBASE) + ldsW]), 16, 0, 0); \
    __builtin_amdgcn_global_load_lds(AS1(s1_), AS3(&lds[(DSTBASE) + 4096 + ldsW]), 16, 0, 0); \
  } while (0)

#define LOADA(BUF, QM)                                                         \
  do {                                                                         \
    const int base_ = A_LDS(BUF, QM);                                          \
    _Pragma("unroll") for (int i_ = 0; i_ < 4; ++i_) {                         \
      const int r_ = wr * 64 + i_ * 16 + fr;                                   \
      const int sw_ = r_ & 7;                                                  \
      aH[i_] = *(const bf16x8*)&lds[base_ + r_ * 64 + ((ksl ^ sw_) << 3)];     \
      aL[i_] = *(const bf16x8*)&lds[base_ + r_ * 64 + (((4 + ksl) ^ sw_) << 3)]; \
    }                                                                          \
  } while (0)

#define LOADB(BUF, QN, BH, BL)                                                 \
  do {                                                                         \
    const int base_ = B_LDS(BUF, QN);                                          \
    _Pragma("unroll") for (int j_ = 0; j_ < 2; ++j_) {                         \
      const int r_ = wc * 32 + j_ * 16 + fr;                                   \
      const int sw_ = r_ & 7;                                                  \
      BH[j_] = *(const bf16x8*)&lds[base_ + r_ * 64 + ((ksl ^ sw_) << 3)];     \
      BL[j_] = *(const bf16x8*)&lds[base_ + r_ * 64 + (((4 + ksl) ^ sw_) << 3)]; \
    }                                                                          \
  } while (0)

#define MMAQ(QM, QN, BH, BL)                                                   \
  do {                                                                         \
    _Pragma("unroll") for (int i_ = 0; i_ < 4; ++i_) {                         \
      _Pragma("unroll") for (int j_ = 0; j_ < 2; ++j_) {                       \
        f32x4 c_ = acc[(QM) * 4 + i_][(QN) * 2 + j_];                          \
        c_ = __builtin_amdgcn_mfma_f32_16x16x32_bf16(aH[i_], BH[j_], c_, 0, 0, 0); \
        c_ = __builtin_amdgcn_mfma_f32_16x16x32_bf16(aH[i_], BL[j_], c_, 0, 0, 0); \
        c_ = __builtin_amdgcn_mfma_f32_16x16x32_bf16(aL[i_], BH[j_], c_, 0, 0, 0); \
        acc[(QM) * 4 + i_][(QN) * 2 + j_] = c_;                                \
      }                                                                        \
    }                                                                          \
  } while (0)

#define PH_PRE()                                                               \
  __builtin_amdgcn_s_barrier();                                                \
  asm volatile("s_waitcnt lgkmcnt(0)" ::: "memory");                           \
  __builtin_amdgcn_s_setprio(1)

#define PH_POST()                                                              \
  __builtin_amdgcn_s_setprio(0);                                               \
  __builtin_amdgcn_s_barrier()

template <int EPI>
__global__ __launch_bounds__(512, 2) void gemm8s(
    const u16* __restrict__ Ah, const u16* __restrict__ Al,
    const u16* __restrict__ Bh, const u16* __restrict__ Bl,
    const float* __restrict__ bias, float* __restrict__ Cf,
    u16* __restrict__ Ch, u16* __restrict__ Cl, int M, int N, int K,
    long long sA, long long sB, long long sC) {
  extern __shared__ u16 lds[];

  const int tt = threadIdx.x;
  const int lane = tt & 63;
  const int wv = tt >> 6;
  const int wr = wv >> 2;  // 0..1
  const int wc = wv & 3;   // 0..3
  const int fr = lane & 15;
  const int ksl = lane >> 4;  // 0..3

  const long long zb = blockIdx.z;
  const u16* pAh = Ah + zb * sA;
  const u16* pAl = Al + zb * sA;
  const u16* pBh = Bh + zb * sB;
  const u16* pBl = Bl + zb * sB;
  const int m0 = blockIdx.x * 256;
  const int n0 = blockIdx.y * 256;

  // staging coords: instr covers 64 rows x 64B; thread -> (row sr, slot ss)
  const int sr = tt >> 3;
  const int ss = tt & 7;
  const int sc = ss ^ (sr & 7);        // global chunk held at slot ss
  const int ldsW = (tt & ~63) * 8;     // wave-uniform LDS base (elements)

  f32x4 acc[8][4] = {};
  bf16x8 aH[4], aL[4], bH0[2], bL0[2], bH1[2], bL1[2];

  const int NT = K / 32;
  const int NITER = NT / 2;

  // prologue: tile0 full + tile1 halves0
  STAGE(A_LDS(0, 0), pAh, pAl, m0, 0);
  STAGE(B_LDS(0, 0), pBh, pBl, n0, 0);
  STAGE(A_LDS(0, 1), pAh, pAl, m0 + 128, 0);
  STAGE(B_LDS(0, 1), pBh, pBl, n0 + 128, 0);
  STAGE(A_LDS(1, 0), pAh, pAl, m0, 32);
  STAGE(B_LDS(1, 0), pBh, pBl, n0, 32);
  asm volatile("s_waitcnt vmcnt(4)" ::: "memory");
  __builtin_amdgcn_s_barrier();
  __builtin_amdgcn_sched_barrier(0);

  for (int it = 0; it < NITER; ++it) {
    const int t0 = 2 * it;
    const int k1 = (t0 + 1) * 32;
    const int k2 = (t0 + 2 < NT ? t0 + 2 : NT - 1) * 32;
    const int k3 = (t0 + 3 < NT ? t0 + 3 : NT - 1) * 32;

    // P1: quad(0,0) buf0 | stage A(1,h1) <- t1
    LOADA(0, 0);
    LOADB(0, 0, bH0, bL0);
    STAGE(A_LDS(1, 1), pAh, pAl, m0 + 128, k1);
    PH_PRE();
    MMAQ(0, 0, bH0, bL0);
    PH_POST();

    // P2: quad(0,1) buf0 | stage B(1,h1) <- t1
    LOADB(0, 1, bH1, bL1);
    STAGE(B_LDS(1, 1), pBh, pBl, n0 + 128, k1);
    PH_PRE();
    MMAQ(0, 1, bH1, bL1);
    PH_POST();

    // P3: quad(1,0) buf0 | stage A(0,h0) <- t2
    LOADA(0, 1);
    STAGE(A_LDS(0, 0), pAh, pAl, m0, k2);
    PH_PRE();
    MMAQ(1, 0, bH0, bL0);
    PH_POST();

    // P4: quad(1,1) buf0 | stage B(0,h0) <- t2 | vmcnt(4)
    STAGE(B_LDS(0, 0), pBh, pBl, n0, k2);
    __builtin_amdgcn_s_barrier();
    asm volatile("s_waitcnt lgkmcnt(0)" ::: "memory");
    __builtin_amdgcn_s_setprio(1);
    MMAQ(1, 1, bH1, bL1);
    __builtin_amdgcn_s_setprio(0);
    asm volatile("s_waitcnt vmcnt(4)" ::: "memory");
    __builtin_amdgcn_s_barrier();
    __builtin_amdgcn_sched_barrier(0);

    // P5: quad(0,0) buf1 | stage A(0,h1) <- t2
    LOADA(1, 0);
    LOADB(1, 0, bH0, bL0);
    STAGE(A_LDS(0, 1), pAh, pAl, m0 + 128, k2);
    PH_PRE();
    MMAQ(0, 0, bH0, bL0);
    PH_POST();

    // P6: quad(0,1) buf1 | stage B(0,h1) <- t2
    LOADB(1, 1, bH1, bL1);
    STAGE(B_LDS(0, 1), pBh, pBl, n0 + 128, k2);
    PH_PRE();
    MMAQ(0, 1, bH1, bL1);
    PH_POST();

    // P7: quad(1,0) buf1 | stage A(1,h0) <- t3
    LOADA(1, 1);
    STAGE(A_LDS(1, 0), pAh, pAl, m0, k3);
    PH_PRE();
    MMAQ(1, 0, bH0, bL0);
    PH_POST();

    // P8: quad(1,1) buf1 | stage B(1,h0) <- t3 | vmcnt(4)
    STAGE(B_LDS(1, 0), pBh, pBl, n0, k3);
    __builtin_amdgcn_s_barrier();
    asm volatile("s_waitcnt lgkmcnt(0)" ::: "memory");
    __builtin_amdgcn_s_setprio(1);
    MMAQ(1, 1, bH1, bL1);
    __builtin_amdgcn_s_setprio(0);
    asm volatile("s_waitcnt vmcnt(4)" ::: "memory");
    __builtin_amdgcn_s_barrier();
    __builtin_amdgcn_sched_barrier(0);
  }

  // epilogue
  const int er = (lane >> 4) * 4;
  const int ec = lane & 15;
#pragma unroll
  for (int fi = 0; fi < 8; ++fi) {
    const int qm = fi >> 2, i = fi & 3;
    const int grow0 = m0 + qm * 128 + wr * 64 + i * 16 + er;
#pragma unroll
    for (int fj = 0; fj < 4; ++fj) {
      const int qn = fj >> 1, j = fj & 1;
      const int gcol = n0 + qn * 128 + wc * 32 + j * 16 + ec;
      const float bv = bias ? bias[gcol] : 0.0f;
#pragma unroll
      for (int r = 0; r < 4; ++r) {
        const float x = acc[fi][fj][r] + bv;
        const size_t off = (size_t)zb * sC + (size_t)(grow0 + r) * N + gcol;
        if constexpr (EPI == 0) {
          Cf[off] = x;
        } else {
          const u16 h = f2bf(x);
          Ch[off] = h;
          Cl[off] = f2bf(x - bf2f(h));
        }
      }
    }
  }
}

// ---------------------------------------------------------------------------
// Row softmax: in-place fp32 (weights output) + bf16 copy (P for PV GEMM).
// ---------------------------------------------------------------------------
__global__ __launch_bounds__(256) void softmax_rows(float* __restrict__ S,
                                                    u16* __restrict__ P) {
  const int T = 2048;
  const size_t row = blockIdx.x;
  float* sr = S + row * T;
  u16* pr = P + row * T;
  const int t = threadIdx.x;
  const int w = t >> 6, lane = t & 63;
  __shared__ float red[8];

  float v[8];
  float mx = -1e30f;
#pragma unroll
  for (int i = 0; i < 8; ++i) {
    v[i] = sr[t + 256 * i];
    mx = fmaxf(mx, v[i]);
  }
#pragma unroll
  for (int off = 32; off; off >>= 1) mx = fmaxf(mx, __shfl_xor(mx, off));
  if (lane == 0) red[w] = mx;
  __syncthreads();
  mx = fmaxf(fmaxf(red[0], red[1]), fmaxf(red[2], red[3]));

  float s = 0.f;
#pragma unroll
  for (int i = 0; i < 8; ++i) {
    v[i] = __expf(v[i] - mx);
    s += v[i];
  }
#pragma unroll
  for (int off = 32; off; off >>= 1) s += __shfl_xor(s, off);
  if (lane == 0) red[4 + w] = s;
  __syncthreads();
  s = (red[4] + red[5]) + (red[6] + red[7]);
  const float inv = 1.0f / s;
#pragma unroll
  for (int i = 0; i < 8; ++i) {
    const float wv = v[i] * inv;
    sr[t + 256 * i] = wv;
    pr[t + 256 * i] = f2bf(wv);
  }
}

// ---------------------------------------------------------------------------
extern "C" void kernel_launch(void* const* d_in, const int* in_sizes, int n_in,
                              void* d_out, int out_size, void* d_ws,
                              size_t ws_size, hipStream_t stream) {
  (void)in_sizes; (void)n_in; (void)out_size; (void)ws_size;
  const float* query = (const float*)d_in[0];
  const float* key   = (const float*)d_in[1];
  const float* value = (const float*)d_in[2];
  const float* Wq    = (const float*)d_in[3];
  const float* bq    = (const float*)d_in[4];
  const float* Wo    = (const float*)d_in[5];
  const float* bo    = (const float*)d_in[6];

  const int S = 2048, D = 1024;
  const size_t n = (size_t)4 * S * D;  // 8,388,608

  float* out = (float*)d_out;
  float* wts = out + n;  // (B,S,T) fp32, 64MB

  char* ws = (char*)d_ws;
  u16* wqt_h = (u16*)(ws);
  u16* wqt_l = (u16*)(ws + (2ull << 20));
  u16* wot   = (u16*)(ws + (4ull << 20));
  u16* vin   = (u16*)(ws + (6ull << 20));   // 16MB, reused as ctx
  u16* QKh   = (u16*)(ws + (22ull << 20));  // 32MB: Q rows then K rows
  u16* QKl   = (u16*)(ws + (54ull << 20));  // 32MB  (total ws use: 86MB)
  u16* P = QKh;     // 32MB (QKh dead after score GEMM)
  u16* ctxb = vin;  // 16MB (vin dead after V projection)

  // scratch in d_out: wts region holds input splits until score GEMM writes;
  // out region holds V / V^T until final GEMM writes.
  u16* qkin_h = (u16*)wts;        // [q(8192 rows); k(8192 rows)]
  u16* qkin_l = qkin_h + 2 * n;
  u16* Vp = (u16*)out;
  u16* Vt = Vp + n;

  hipFuncSetAttribute((const void*)&gemm8s<2>,
                      hipFuncAttributeMaxDynamicSharedMemorySize, 131072);
  hipFuncSetAttribute((const void*)&gemm8s<0>,
                      hipFuncAttributeMaxDynamicSharedMemorySize, 131072);

  // 1. split q,k inputs (stacked); bf16 v
  split_qkv<<<2048, 256, 0, stream>>>(query, key, value, qkin_h, qkin_l,
                                      qkin_h + n, qkin_l + n, vin, (int)(n / 4));
  // 2. weight transpose+split (tiled)
  prep_w_t<<<dim3(D / 32, D / 32), dim3(32, 8), 0, stream>>>(Wq, Wo, wqt_h,
                                                             wqt_l, wot, D);
  // 3. [Q;K] = [q;k] @ Wq + bq  (split in, split out) — 8-phase 256^2
  gemm8s<2><<<dim3(64, 4, 1), 512, 131072, stream>>>(
      qkin_h, qkin_l, wqt_h, wqt_l, bq, nullptr, QKh, QKl, 16384, 1024, 1024,
      0, 0, 0);
  // 4. V = value @ Wq + bq  (plain bf16)
  gemm_bt<1><<<dim3(64, 8, 1), 256, 0, stream>>>(
      vin, wqt_h, bq, nullptr, Vp, 8192, 1024, 1024, 0, 0, 0);
  // 5. V^T per batch (2048x1024 -> 1024x2048)
  transpose_bf16<<<dim3(1024 / 32, 2048 / 32, 4), dim3(32, 8), 0, stream>>>(
      Vp, Vt, 2048, 1024);
  // 6. score = Q @ K^T (split, fp32 out into weights region) — 8-phase 256^2
  gemm8s<0><<<dim3(8, 8, 4), 512, 131072, stream>>>(
      QKh, QKl, QKh + n, QKl + n, nullptr, wts, nullptr, nullptr, 2048, 2048,
      1024, (long long)S * D, (long long)S * D, (long long)S * S);
  // 7. softmax rows (in-place) + bf16 P
  softmax_rows<<<8192, 256, 0, stream>>>(wts, P);
  // 8. ctx = P @ V  (Bt = V^T)
  gemm_bt<1><<<dim3(16, 8, 4), 256, 0, stream>>>(
      P, Vt, nullptr, nullptr, ctxb, 2048, 1024, 2048, (long long)S * S,
      (long long)D * S, (long long)S * D);
  // 9. out = ctx @ Wo + bo (fp32 out)
  gemm_bt<0><<<dim3(64, 8, 1), 256, 0, stream>>>(
      ctxb, wot, bo, out, nullptr, 8192, 1024, 1024, 0, 0, 0);
}